// Round 3
// baseline (843.376 us; speedup 1.0000x reference)
//
#include <hip/hip_runtime.h>
#include <hip/hip_fp16.h>

#define NEG_SLOPE 0.2f
#define FINF __builtin_inff()

// ================= prologue kernels (once per call) =================

__global__ __launch_bounds__(256) void k_deg(const int* __restrict__ dst,
                                             int* __restrict__ deg, int ne) {
    int e = blockIdx.x * blockDim.x + threadIdx.x;
    if (e < ne) atomicAdd(&deg[dst[e]], 1);
}

// single-block exclusive scan over deg[0..n) -> rowptr[0..n], cursor copy
// int4-vectorized: 4096 elements per sweep
__global__ __launch_bounds__(1024) void k_scan(const int* __restrict__ deg,
                                               int* __restrict__ rowptr,
                                               int* __restrict__ cursor, int n) {
    __shared__ int wsum[16];
    __shared__ int carry_s;
    int t = threadIdx.x, lane = t & 63, w = t >> 6;
    if (t == 0) carry_s = 0;
    __syncthreads();
    for (int base = 0; base < n; base += 4096) {
        int i0 = base + t * 4;
        int4 v;
        v.x = (i0 + 0 < n) ? deg[i0 + 0] : 0;
        v.y = (i0 + 1 < n) ? deg[i0 + 1] : 0;
        v.z = (i0 + 2 < n) ? deg[i0 + 2] : 0;
        v.w = (i0 + 3 < n) ? deg[i0 + 3] : 0;
        int tsum = v.x + v.y + v.z + v.w;
        int s = tsum;
        #pragma unroll
        for (int off = 1; off < 64; off <<= 1) {
            int y = __shfl_up(s, off);
            if (lane >= off) s += y;
        }
        if (lane == 63) wsum[w] = s;
        __syncthreads();
        if (w == 0 && lane < 16) {
            int ws = wsum[lane];
            #pragma unroll
            for (int off = 1; off < 16; off <<= 1) {
                int y = __shfl_up(ws, off);
                if (lane >= off) ws += y;
            }
            wsum[lane] = ws;   // inclusive scan of wave sums
        }
        __syncthreads();
        int carry = carry_s;
        int wexcl = (w > 0) ? wsum[w - 1] : 0;
        int excl = carry + wexcl + (s - tsum);   // exclusive prefix for elem i0
        int e0 = excl;
        int e1 = e0 + v.x;
        int e2 = e1 + v.y;
        int e3 = e2 + v.z;
        if (i0 + 0 < n) { rowptr[i0 + 0] = e0; cursor[i0 + 0] = e0; }
        if (i0 + 1 < n) { rowptr[i0 + 1] = e1; cursor[i0 + 1] = e1; }
        if (i0 + 2 < n) { rowptr[i0 + 2] = e2; cursor[i0 + 2] = e2; }
        if (i0 + 3 < n) { rowptr[i0 + 3] = e3; cursor[i0 + 3] = e3; }
        __syncthreads();
        if (t == 0) carry_s = carry + wsum[15];
        __syncthreads();
    }
    if (t == 0) rowptr[n] = carry_s;
}

__global__ __launch_bounds__(256) void k_scatter(const int* __restrict__ src,
                                                 const int* __restrict__ dst,
                                                 int* __restrict__ cursor,
                                                 int* __restrict__ csr_src, int ne) {
    int e = blockIdx.x * blockDim.x + threadIdx.x;
    if (e >= ne) return;
    int pos = atomicAdd(&cursor[dst[e]], 1);
    csr_src[pos] = src[e];
}

// W[l][k][h*64+f] -> Wt[l][k][f*4+h]   (all 4 layers)
__global__ __launch_bounds__(256) void k_transW(const float* __restrict__ W,
                                                float* __restrict__ Wt) {
    int i = blockIdx.x * blockDim.x + threadIdx.x;
    if (i >= 4 * 64 * 256) return;
    int l = i >> 14, r = i & 16383;
    int k = r >> 8, c = r & 255;
    int f = c >> 2, h = c & 3;
    Wt[i] = W[(l << 14) + (k << 8) + h * 64 + f];
}

// al/ar[l][h][f] -> alT/arT[l][f*4+h]; bsum[l][f] = sum_h bias[l][h][f]
__global__ __launch_bounds__(256) void k_transA(const float* __restrict__ al,
                                                const float* __restrict__ ar,
                                                const float* __restrict__ bias,
                                                float* __restrict__ alT,
                                                float* __restrict__ arT,
                                                float* __restrict__ bsum) {
    int i = blockIdx.x * blockDim.x + threadIdx.x;
    if (i < 4 * 256) {
        int l = i >> 8, c = i & 255;
        int f = c >> 2, h = c & 3;
        alT[i] = al[(l << 8) + h * 64 + f];
        arT[i] = ar[(l << 8) + h * 64 + f];
    }
    if (i < 4 * 64) {
        int l = i >> 6, f = i & 63;
        float s = 0.f;
        #pragma unroll
        for (int h = 0; h < 4; ++h) s += bias[(l << 8) + h * 64 + f];
        bsum[i] = s;
    }
}

// ================= per-layer kernels =================

// ft = h @ W, shuffle-free. Block = 256 thr = 4 waves over 64 rows.
// LDS h-tile [64 rows][64 k] stride 65. Wave w owns columns c0=w*64..+63,
// lane = row. W operand is wave-uniform (scalar loads). Fused el/er dots.
// ft output is fp16, layout [row][f*4+h].
__global__ __launch_bounds__(256) void k_gemm(
        const float* __restrict__ h, const float* __restrict__ Wt,
        const float* __restrict__ alT, const float* __restrict__ arT,
        __half* __restrict__ ft, float* __restrict__ el, float* __restrict__ er,
        int n) {
    __shared__ float hs[64 * 65];
    __shared__ float4 red[2][4][64];   // el/er partials per wave per row
    int t = threadIdx.x, w = t >> 6, lane = t & 63;
    int r0 = blockIdx.x * 64;

    // stage h-tile (coalesced: wave w loads rows w*16..w*16+15)
    #pragma unroll 4
    for (int i = 0; i < 16; ++i) {
        int row = w * 16 + i;
        int gr = r0 + row;
        hs[row * 65 + lane] = (gr < n) ? h[(size_t)gr * 64 + lane] : 0.f;
    }
    __syncthreads();

    int c0 = w * 64;
    float acc[64];
    #pragma unroll
    for (int c = 0; c < 64; ++c) acc[c] = 0.f;

    const float* Wp = Wt + c0;
    #pragma unroll 2
    for (int k = 0; k < 64; ++k) {
        float hv = hs[lane * 65 + k];
        const float* wr = Wp + (k << 8);
        #pragma unroll
        for (int c = 0; c < 64; ++c) acc[c] = fmaf(hv, wr[c], acc[c]);
    }

    // el/er partial dots over this wave's 64 columns (h = c&3 since c0%4==0)
    float elp0 = 0.f, elp1 = 0.f, elp2 = 0.f, elp3 = 0.f;
    float erp0 = 0.f, erp1 = 0.f, erp2 = 0.f, erp3 = 0.f;
    const float* alp = alT + c0;
    const float* arp = arT + c0;
    #pragma unroll
    for (int c = 0; c < 64; c += 4) {
        elp0 = fmaf(acc[c + 0], alp[c + 0], elp0);
        elp1 = fmaf(acc[c + 1], alp[c + 1], elp1);
        elp2 = fmaf(acc[c + 2], alp[c + 2], elp2);
        elp3 = fmaf(acc[c + 3], alp[c + 3], elp3);
        erp0 = fmaf(acc[c + 0], arp[c + 0], erp0);
        erp1 = fmaf(acc[c + 1], arp[c + 1], erp1);
        erp2 = fmaf(acc[c + 2], arp[c + 2], erp2);
        erp3 = fmaf(acc[c + 3], arp[c + 3], erp3);
    }
    red[0][w][lane] = make_float4(elp0, elp1, elp2, elp3);
    red[1][w][lane] = make_float4(erp0, erp1, erp2, erp3);

    // store ft row-chunk as fp16 (64 halves = 8 uint4)
    int gr = r0 + lane;
    if (gr < n) {
        uint4* dstp = (uint4*)(ft + (size_t)gr * 256 + c0);
        #pragma unroll
        for (int q = 0; q < 8; ++q) {
            uint4 v;
            v.x = (uint)__half_as_ushort(__float2half_rn(acc[q * 8 + 0])) |
                  ((uint)__half_as_ushort(__float2half_rn(acc[q * 8 + 1])) << 16);
            v.y = (uint)__half_as_ushort(__float2half_rn(acc[q * 8 + 2])) |
                  ((uint)__half_as_ushort(__float2half_rn(acc[q * 8 + 3])) << 16);
            v.z = (uint)__half_as_ushort(__float2half_rn(acc[q * 8 + 4])) |
                  ((uint)__half_as_ushort(__float2half_rn(acc[q * 8 + 5])) << 16);
            v.w = (uint)__half_as_ushort(__float2half_rn(acc[q * 8 + 6])) |
                  ((uint)__half_as_ushort(__float2half_rn(acc[q * 8 + 7])) << 16);
            dstp[q] = v;
        }
    }

    __syncthreads();
    // reduce el/er partials across the 4 waves: thread t -> (row, hh)
    int row = t >> 2, hh = t & 3;
    float se = ((float*)&red[0][0][row])[hh] + ((float*)&red[0][1][row])[hh] +
               ((float*)&red[0][2][row])[hh] + ((float*)&red[0][3][row])[hh];
    float sr = ((float*)&red[1][0][row])[hh] + ((float*)&red[1][1][row])[hh] +
               ((float*)&red[1][2][row])[hh] + ((float*)&red[1][3][row])[hh];
    if (r0 + row < n) {
        el[(size_t)(r0 + row) * 4 + hh] = se;
        er[(size_t)(r0 + row) * 4 + hh] = sr;
    }
}

// Fused edge-softmax + aggregation + bias. One wave per dst node.
// lane = (ei<<2)|h for softmax phases; lane = feature group for aggregation.
__global__ __launch_bounds__(256) void k_agg(
        const int* __restrict__ rowptr, const int* __restrict__ csr_src,
        const float* __restrict__ el, const float* __restrict__ er,
        const __half* __restrict__ ft, const float* __restrict__ bsum,
        float* __restrict__ out, int n) {
    __shared__ float lds_ee[4][64];
    __shared__ int   lds_s[4][16];
    int wid  = (int)((blockIdx.x * blockDim.x + threadIdx.x) >> 6);
    int w    = (threadIdx.x >> 6) & 3;
    int lane = threadIdx.x & 63;
    if (wid >= n) return;
    int d = wid;
    int rbeg = rowptr[d], rend = rowptr[d + 1];
    float bs = bsum[lane];
    if (rend == rbeg) { out[(size_t)d * 64 + lane] = bs; return; }

    int ei = lane >> 2, hh = lane & 3;
    float erh = er[(size_t)d * 4 + hh];

    // pass 1: per-head max over incoming edges
    float m = -FINF;
    for (int base = rbeg; base < rend; base += 16) {
        int idx = base + ei;
        float ev = -FINF;
        if (idx < rend) {
            int s = csr_src[idx];
            float x = el[(size_t)s * 4 + hh] + erh;
            ev = x > 0.f ? x : NEG_SLOPE * x;
        }
        m = fmaxf(m, ev);
    }
    #pragma unroll
    for (int msk = 4; msk < 64; msk <<= 1) m = fmaxf(m, __shfl_xor(m, msk));

    // pass 2: ee = exp(e - m); accumulate denom and unnormalized per-head sums
    float dsum = 0.f;
    float4 acc = make_float4(0.f, 0.f, 0.f, 0.f);
    for (int base = rbeg; base < rend; base += 16) {
        int idx = base + ei;
        int e16 = min(16, rend - base);
        float ee = 0.f;
        if (idx < rend) {
            int s = csr_src[idx];
            float x = el[(size_t)s * 4 + hh] + erh;
            x = x > 0.f ? x : NEG_SLOPE * x;
            ee = __expf(x - m);
            dsum += ee;
            if (hh == 0) lds_s[w][ei] = s;
        }
        lds_ee[w][lane] = ee;
        for (int i = 0; i < e16; ++i) {
            float4 ee4 = *(float4*)&lds_ee[w][i * 4];
            int s = lds_s[w][i];
            uint2 u = *(const uint2*)(ft + (size_t)s * 256 + (lane << 2));
            float2 fa = __half22float2(*(__half2*)&u.x);
            float2 fb = __half22float2(*(__half2*)&u.y);
            acc.x += ee4.x * fa.x; acc.y += ee4.y * fa.y;
            acc.z += ee4.z * fb.x; acc.w += ee4.w * fb.y;
        }
    }
    #pragma unroll
    for (int msk = 4; msk < 64; msk <<= 1) dsum += __shfl_xor(dsum, msk);
    float d0 = __shfl(dsum, 0), d1 = __shfl(dsum, 1);
    float d2 = __shfl(dsum, 2), d3 = __shfl(dsum, 3);
    out[(size_t)d * 64 + lane] = acc.x / d0 + acc.y / d1 + acc.z / d2 + acc.w / d3 + bs;
}

// ================= launcher =================

extern "C" void kernel_launch(void* const* d_in, const int* in_sizes, int n_in,
                              void* d_out, int out_size, void* d_ws, size_t ws_size,
                              hipStream_t stream) {
    const float* feat = (const float*)d_in[0];
    const float* W    = (const float*)d_in[1];
    const float* al   = (const float*)d_in[2];
    const float* ar   = (const float*)d_in[3];
    const float* bias = (const float*)d_in[4];
    const int*   src  = (const int*)d_in[5];
    const int*   dst  = (const int*)d_in[6];
    float* out = (float*)d_out;

    const int N = in_sizes[0] / 64;   // 50000
    const int E = in_sizes[5];        // 500000
    const int L = 4;

    // workspace carve
    float* ws = (float*)d_ws;
    __half* ft = (__half*)ws;                          // N*256 halves = N*128 floats
    float* hA   = ws + (size_t)N * 128;                // N*64
    float* hB   = hA + (size_t)N * 64;                 // N*64
    float* el   = hB + (size_t)N * 64;                 // N*4
    float* er   = el + (size_t)N * 4;                  // N*4
    float* Wt   = er + (size_t)N * 4;                  // 4*16384
    float* alT  = Wt + 4 * 16384;                      // 4*256
    float* arT  = alT + 4 * 256;                       // 4*256
    float* bsum = arT + 4 * 256;                       // 4*64
    int* rowptr  = (int*)(bsum + 4 * 64);              // N+1
    int* cursor  = rowptr + (N + 1);                   // N
    int* deg     = cursor + N;                         // N
    int* csr_src = deg + N;                            // E

    // ---- prologue: CSR build + weight transposes (once per call) ----
    hipMemsetAsync(deg, 0, (size_t)N * sizeof(int), stream);
    k_deg<<<(E + 255) / 256, 256, 0, stream>>>(dst, deg, E);
    k_scan<<<1, 1024, 0, stream>>>(deg, rowptr, cursor, N);
    k_scatter<<<(E + 255) / 256, 256, 0, stream>>>(src, dst, cursor, csr_src, E);
    k_transW<<<(4 * 64 * 256 + 255) / 256, 256, 0, stream>>>(W, Wt);
    k_transA<<<4, 256, 0, stream>>>(al, ar, bias, alT, arT, bsum);

    // ---- layers ----
    const float* hin = feat;
    for (int l = 0; l < L; ++l) {
        float* hout = (l == L - 1) ? out : ((l & 1) ? hB : hA);
        k_gemm<<<(N + 63) / 64, 256, 0, stream>>>(
            hin, Wt + (size_t)l * 16384, alT + (size_t)l * 256,
            arT + (size_t)l * 256, ft, el, er, N);
        k_agg<<<((size_t)N * 64 + 255) / 256, 256, 0, stream>>>(
            rowptr, csr_src, el, er, ft, bsum + (size_t)l * 64, hout, N);
        hin = hout;
    }
}

// Round 4
// 449.421 us; speedup vs baseline: 1.8766x; 1.8766x over previous
//
#include <hip/hip_runtime.h>
#include <hip/hip_fp16.h>

#define NEG_SLOPE 0.2f
#define FINF __builtin_inff()

// ================= prologue kernels (once per call) =================

__global__ __launch_bounds__(256) void k_deg(const int* __restrict__ dst,
                                             int* __restrict__ deg, int ne) {
    int e = blockIdx.x * blockDim.x + threadIdx.x;
    if (e < ne) atomicAdd(&deg[dst[e]], 1);
}

// single-block exclusive scan over deg[0..n) -> rowptr[0..n], cursor copy
__global__ __launch_bounds__(1024) void k_scan(const int* __restrict__ deg,
                                               int* __restrict__ rowptr,
                                               int* __restrict__ cursor, int n) {
    __shared__ int wsum[16];
    __shared__ int carry_s;
    int t = threadIdx.x, lane = t & 63, w = t >> 6;
    if (t == 0) carry_s = 0;
    __syncthreads();
    for (int base = 0; base < n; base += 4096) {
        int i0 = base + t * 4;
        int4 v;
        v.x = (i0 + 0 < n) ? deg[i0 + 0] : 0;
        v.y = (i0 + 1 < n) ? deg[i0 + 1] : 0;
        v.z = (i0 + 2 < n) ? deg[i0 + 2] : 0;
        v.w = (i0 + 3 < n) ? deg[i0 + 3] : 0;
        int tsum = v.x + v.y + v.z + v.w;
        int s = tsum;
        #pragma unroll
        for (int off = 1; off < 64; off <<= 1) {
            int y = __shfl_up(s, off);
            if (lane >= off) s += y;
        }
        if (lane == 63) wsum[w] = s;
        __syncthreads();
        if (w == 0 && lane < 16) {
            int ws = wsum[lane];
            #pragma unroll
            for (int off = 1; off < 16; off <<= 1) {
                int y = __shfl_up(ws, off);
                if (lane >= off) ws += y;
            }
            wsum[lane] = ws;   // inclusive scan of wave sums
        }
        __syncthreads();
        int carry = carry_s;
        int wexcl = (w > 0) ? wsum[w - 1] : 0;
        int excl = carry + wexcl + (s - tsum);
        int e0 = excl;
        int e1 = e0 + v.x;
        int e2 = e1 + v.y;
        int e3 = e2 + v.z;
        if (i0 + 0 < n) { rowptr[i0 + 0] = e0; cursor[i0 + 0] = e0; }
        if (i0 + 1 < n) { rowptr[i0 + 1] = e1; cursor[i0 + 1] = e1; }
        if (i0 + 2 < n) { rowptr[i0 + 2] = e2; cursor[i0 + 2] = e2; }
        if (i0 + 3 < n) { rowptr[i0 + 3] = e3; cursor[i0 + 3] = e3; }
        __syncthreads();
        if (t == 0) carry_s = carry + wsum[15];
        __syncthreads();
    }
    if (t == 0) rowptr[n] = carry_s;
}

__global__ __launch_bounds__(256) void k_scatter(const int* __restrict__ src,
                                                 const int* __restrict__ dst,
                                                 int* __restrict__ cursor,
                                                 int* __restrict__ csr_src, int ne) {
    int e = blockIdx.x * blockDim.x + threadIdx.x;
    if (e >= ne) return;
    int pos = atomicAdd(&cursor[dst[e]], 1);
    csr_src[pos] = src[e];
}

// W[l][k][h*64+f] -> Wt[l][k][f*4+h]   (all 4 layers)
__global__ __launch_bounds__(256) void k_transW(const float* __restrict__ W,
                                                float* __restrict__ Wt) {
    int i = blockIdx.x * blockDim.x + threadIdx.x;
    if (i >= 4 * 64 * 256) return;
    int l = i >> 14, r = i & 16383;
    int k = r >> 8, c = r & 255;
    int f = c >> 2, h = c & 3;
    Wt[i] = W[(l << 14) + (k << 8) + h * 64 + f];
}

// WAB[l][k][j] : j<4 -> sum_f W[l][k][j*64+f]*al[l][j][f]; j>=4 -> ar (head j-4).
// bsum[l][f] = sum_h bias[l][h][f]
__global__ __launch_bounds__(256) void k_prep(const float* __restrict__ W,
                                              const float* __restrict__ al,
                                              const float* __restrict__ ar,
                                              const float* __restrict__ bias,
                                              float* __restrict__ WAB,
                                              float* __restrict__ bsum) {
    int i = blockIdx.x * blockDim.x + threadIdx.x;
    if (i < 4 * 64 * 8) {
        int l = i >> 9, r = i & 511;
        int k = r >> 3, j = r & 7;
        int hh = j & 3;
        const float* wrow = W + (l << 14) + (k << 8) + hh * 64;
        const float* av = ((j < 4) ? al : ar) + (l << 8) + hh * 64;
        float s = 0.f;
        #pragma unroll 8
        for (int f = 0; f < 64; ++f) s = fmaf(wrow[f], av[f], s);
        WAB[i] = s;
    }
    int i2 = i - 4 * 64 * 8;
    if (i2 >= 0 && i2 < 4 * 64) {
        int l = i2 >> 6, f = i2 & 63;
        float s = 0.f;
        #pragma unroll
        for (int h = 0; h < 4; ++h) s += bias[(l << 8) + h * 64 + f];
        bsum[i2] = s;
    }
}

// ================= per-layer kernels =================

// ft = h @ W. Block = 256 thr = 4 waves, 32-row chunk.
// W staged in LDS (64KB). hT[k][row] transposed tile (stride 36).
// Thread: cols c0=(t&63)*4 (one f-group, 4 heads), rows (t>>6)*8..+7.
// el/er fused via precomputed WAB (no cross-lane ops).
__global__ __launch_bounds__(256) void k_gemm(
        const float* __restrict__ h, const float* __restrict__ Wt,
        const float* __restrict__ WAB,
        __half* __restrict__ ft, float* __restrict__ el, float* __restrict__ er,
        int n) {
    __shared__ float Wls[16384];      // 64KB
    __shared__ float hT[64 * 36];     // 9KB, transposed h tile
    __shared__ float wab[512];        // 2KB
    int t = threadIdx.x, w = t >> 6, lane = t & 63;
    int r0 = blockIdx.x * 32;

    // stage W (linear copy, float4)
    const float4* Wv = (const float4*)Wt;
    float4* Wl4 = (float4*)Wls;
    #pragma unroll
    for (int i = 0; i < 16; ++i) Wl4[t + i * 256] = Wv[t + i * 256];
    if (t < 128) ((float4*)wab)[t] = ((const float4*)WAB)[t];
    // stage hT (coalesced read, transposed write)
    #pragma unroll
    for (int i = 0; i < 8; ++i) {
        int idx = t + i * 256;
        int r = idx >> 6, k = idx & 63;
        int gr = r0 + r;
        hT[k * 36 + r] = (gr < n) ? h[(size_t)gr * 64 + k] : 0.f;
    }
    __syncthreads();

    float4 acc[8];
    #pragma unroll
    for (int j = 0; j < 8; ++j) acc[j] = make_float4(0.f, 0.f, 0.f, 0.f);
    int c0 = lane << 2;
    int hbase = w * 8;

    #pragma unroll 2
    for (int k = 0; k < 64; ++k) {
        float4 w4 = *(const float4*)&Wls[(k << 8) + c0];
        float4 ha = *(const float4*)&hT[k * 36 + hbase];
        float4 hb = *(const float4*)&hT[k * 36 + hbase + 4];
        #define FMA4(A, s) { A.x = fmaf(s, w4.x, A.x); A.y = fmaf(s, w4.y, A.y); \
                             A.z = fmaf(s, w4.z, A.z); A.w = fmaf(s, w4.w, A.w); }
        FMA4(acc[0], ha.x) FMA4(acc[1], ha.y) FMA4(acc[2], ha.z) FMA4(acc[3], ha.w)
        FMA4(acc[4], hb.x) FMA4(acc[5], hb.y) FMA4(acc[6], hb.z) FMA4(acc[7], hb.w)
        #undef FMA4
    }

    // store ft as fp16
    #pragma unroll
    for (int j = 0; j < 8; ++j) {
        int gr = r0 + hbase + j;
        if (gr < n) {
            __half2 lo = __floats2half2_rn(acc[j].x, acc[j].y);
            __half2 hi = __floats2half2_rn(acc[j].z, acc[j].w);
            uint2 v = make_uint2(*(unsigned*)&lo, *(unsigned*)&hi);
            *(uint2*)(ft + (size_t)gr * 256 + c0) = v;
        }
    }

    // el/er from hT and WAB: thread -> (row r2, j) ; j<4: el head j, j>=4: er
    int r2 = t >> 3, j = t & 7;
    float s = 0.f;
    #pragma unroll 8
    for (int k = 0; k < 64; ++k) s = fmaf(hT[k * 36 + r2], wab[(k << 3) + j], s);
    int gr2 = r0 + r2;
    if (gr2 < n) {
        float* dstp = (j < 4) ? el : er;
        dstp[(size_t)gr2 * 4 + (j & 3)] = s;
    }
}

// Fused edge-softmax + aggregation + bias. One wave per dst node.
__global__ __launch_bounds__(256) void k_agg(
        const int* __restrict__ rowptr, const int* __restrict__ csr_src,
        const float* __restrict__ el, const float* __restrict__ er,
        const __half* __restrict__ ft, const float* __restrict__ bsum,
        float* __restrict__ out, int n) {
    __shared__ float lds_ee[4][64];
    __shared__ int   lds_s[4][16];
    int wid  = (int)((blockIdx.x * blockDim.x + threadIdx.x) >> 6);
    int w    = (threadIdx.x >> 6) & 3;
    int lane = threadIdx.x & 63;
    if (wid >= n) return;
    int d = wid;
    int rbeg = rowptr[d], rend = rowptr[d + 1];
    float bs = bsum[lane];
    if (rend == rbeg) { out[(size_t)d * 64 + lane] = bs; return; }

    int ei = lane >> 2, hh = lane & 3;
    float erh = er[(size_t)d * 4 + hh];

    // pass 1: per-head max over incoming edges
    float m = -FINF;
    for (int base = rbeg; base < rend; base += 16) {
        int idx = base + ei;
        float ev = -FINF;
        if (idx < rend) {
            int s = csr_src[idx];
            float x = el[(size_t)s * 4 + hh] + erh;
            ev = x > 0.f ? x : NEG_SLOPE * x;
        }
        m = fmaxf(m, ev);
    }
    #pragma unroll
    for (int msk = 4; msk < 64; msk <<= 1) m = fmaxf(m, __shfl_xor(m, msk));

    // pass 2: ee = exp(e - m); accumulate denom and unnormalized per-head sums
    float dsum = 0.f;
    float4 acc = make_float4(0.f, 0.f, 0.f, 0.f);
    for (int base = rbeg; base < rend; base += 16) {
        int idx = base + ei;
        int e16 = min(16, rend - base);
        float ee = 0.f;
        if (idx < rend) {
            int s = csr_src[idx];
            float x = el[(size_t)s * 4 + hh] + erh;
            x = x > 0.f ? x : NEG_SLOPE * x;
            ee = __expf(x - m);
            dsum += ee;
            if (hh == 0) lds_s[w][ei] = s;
        }
        lds_ee[w][lane] = ee;
        for (int i = 0; i < e16; ++i) {
            float4 ee4 = *(float4*)&lds_ee[w][i * 4];
            int s = lds_s[w][i];
            uint2 u = *(const uint2*)(ft + (size_t)s * 256 + (lane << 2));
            float2 fa = __half22float2(*(__half2*)&u.x);
            float2 fb = __half22float2(*(__half2*)&u.y);
            acc.x += ee4.x * fa.x; acc.y += ee4.y * fa.y;
            acc.z += ee4.z * fb.x; acc.w += ee4.w * fb.y;
        }
    }
    #pragma unroll
    for (int msk = 4; msk < 64; msk <<= 1) dsum += __shfl_xor(dsum, msk);
    float d0 = __shfl(dsum, 0), d1 = __shfl(dsum, 1);
    float d2 = __shfl(dsum, 2), d3 = __shfl(dsum, 3);
    out[(size_t)d * 64 + lane] = acc.x / d0 + acc.y / d1 + acc.z / d2 + acc.w / d3 + bs;
}

// ================= launcher =================

extern "C" void kernel_launch(void* const* d_in, const int* in_sizes, int n_in,
                              void* d_out, int out_size, void* d_ws, size_t ws_size,
                              hipStream_t stream) {
    const float* feat = (const float*)d_in[0];
    const float* W    = (const float*)d_in[1];
    const float* al   = (const float*)d_in[2];
    const float* ar   = (const float*)d_in[3];
    const float* bias = (const float*)d_in[4];
    const int*   src  = (const int*)d_in[5];
    const int*   dst  = (const int*)d_in[6];
    float* out = (float*)d_out;

    const int N = in_sizes[0] / 64;   // 50000
    const int E = in_sizes[5];        // 500000
    const int L = 4;

    // workspace carve
    float* ws = (float*)d_ws;
    __half* ft = (__half*)ws;                          // N*256 halves = N*128 floats
    float* hA   = ws + (size_t)N * 128;                // N*64
    float* hB   = hA + (size_t)N * 64;                 // N*64
    float* el   = hB + (size_t)N * 64;                 // N*4
    float* er   = el + (size_t)N * 4;                  // N*4
    float* Wt   = er + (size_t)N * 4;                  // 4*16384
    float* WAB  = Wt + 4 * 16384;                      // 4*512
    float* bsum = WAB + 4 * 512;                       // 4*64
    int* rowptr  = (int*)(bsum + 4 * 64);              // N+1
    int* cursor  = rowptr + (N + 1);                   // N
    int* deg     = cursor + N;                         // N
    int* csr_src = deg + N;                            // E

    // ---- prologue: CSR build + weight prep (once per call) ----
    hipMemsetAsync(deg, 0, (size_t)N * sizeof(int), stream);
    k_deg<<<(E + 255) / 256, 256, 0, stream>>>(dst, deg, E);
    k_scan<<<1, 1024, 0, stream>>>(deg, rowptr, cursor, N);
    k_scatter<<<(E + 255) / 256, 256, 0, stream>>>(src, dst, cursor, csr_src, E);
    k_transW<<<(4 * 64 * 256 + 255) / 256, 256, 0, stream>>>(W, Wt);
    k_prep<<<(4 * 64 * 8 + 4 * 64 + 255) / 256, 256, 0, stream>>>(
        W, al, ar, bias, WAB, bsum);

    // ---- layers ----
    const float* hin = feat;
    for (int l = 0; l < L; ++l) {
        float* hout = (l == L - 1) ? out : ((l & 1) ? hB : hA);
        k_gemm<<<(N + 31) / 32, 256, 0, stream>>>(
            hin, Wt + (size_t)l * 16384, WAB + (size_t)l * 512,
            ft, el, er, N);
        k_agg<<<((size_t)N * 64 + 255) / 256, 256, 0, stream>>>(
            rowptr, csr_src, el, er, ft, bsum + (size_t)l * 64, hout, N);
        hin = hout;
    }
}

// Round 5
// 419.268 us; speedup vs baseline: 2.0115x; 1.0719x over previous
//
#include <hip/hip_runtime.h>
#include <hip/hip_fp16.h>

#define NEG_SLOPE 0.2f
#define FINF __builtin_inff()

// ================= prologue kernels (once per call) =================

__global__ __launch_bounds__(256) void k_deg(const int* __restrict__ dst,
                                             int* __restrict__ deg, int ne) {
    int e = blockIdx.x * blockDim.x + threadIdx.x;
    if (e < ne) atomicAdd(&deg[dst[e]], 1);
}

__global__ __launch_bounds__(1024) void k_scan(const int* __restrict__ deg,
                                               int* __restrict__ rowptr,
                                               int* __restrict__ cursor, int n) {
    __shared__ int wsum[16];
    __shared__ int carry_s;
    int t = threadIdx.x, lane = t & 63, w = t >> 6;
    if (t == 0) carry_s = 0;
    __syncthreads();
    for (int base = 0; base < n; base += 4096) {
        int i0 = base + t * 4;
        int4 v;
        v.x = (i0 + 0 < n) ? deg[i0 + 0] : 0;
        v.y = (i0 + 1 < n) ? deg[i0 + 1] : 0;
        v.z = (i0 + 2 < n) ? deg[i0 + 2] : 0;
        v.w = (i0 + 3 < n) ? deg[i0 + 3] : 0;
        int tsum = v.x + v.y + v.z + v.w;
        int s = tsum;
        #pragma unroll
        for (int off = 1; off < 64; off <<= 1) {
            int y = __shfl_up(s, off);
            if (lane >= off) s += y;
        }
        if (lane == 63) wsum[w] = s;
        __syncthreads();
        if (w == 0 && lane < 16) {
            int ws = wsum[lane];
            #pragma unroll
            for (int off = 1; off < 16; off <<= 1) {
                int y = __shfl_up(ws, off);
                if (lane >= off) ws += y;
            }
            wsum[lane] = ws;
        }
        __syncthreads();
        int carry = carry_s;
        int wexcl = (w > 0) ? wsum[w - 1] : 0;
        int excl = carry + wexcl + (s - tsum);
        int e0 = excl;
        int e1 = e0 + v.x;
        int e2 = e1 + v.y;
        int e3 = e2 + v.z;
        if (i0 + 0 < n) { rowptr[i0 + 0] = e0; cursor[i0 + 0] = e0; }
        if (i0 + 1 < n) { rowptr[i0 + 1] = e1; cursor[i0 + 1] = e1; }
        if (i0 + 2 < n) { rowptr[i0 + 2] = e2; cursor[i0 + 2] = e2; }
        if (i0 + 3 < n) { rowptr[i0 + 3] = e3; cursor[i0 + 3] = e3; }
        __syncthreads();
        if (t == 0) carry_s = carry + wsum[15];
        __syncthreads();
    }
    if (t == 0) rowptr[n] = carry_s;
}

__global__ __launch_bounds__(256) void k_scatter(const int* __restrict__ src,
                                                 const int* __restrict__ dst,
                                                 int* __restrict__ cursor,
                                                 int* __restrict__ csr_src, int ne) {
    int e = blockIdx.x * blockDim.x + threadIdx.x;
    if (e >= ne) return;
    int pos = atomicAdd(&cursor[dst[e]], 1);
    csr_src[pos] = src[e];
}

// W[l][k][h*64+f] -> Wt[l][k][f*4+h]   (all 4 layers)
__global__ __launch_bounds__(256) void k_transW(const float* __restrict__ W,
                                                float* __restrict__ Wt) {
    int i = blockIdx.x * blockDim.x + threadIdx.x;
    if (i >= 4 * 64 * 256) return;
    int l = i >> 14, r = i & 16383;
    int k = r >> 8, c = r & 255;
    int f = c >> 2, h = c & 3;
    Wt[i] = W[(l << 14) + (k << 8) + h * 64 + f];
}

// WAB[l][k][j]: j<4 -> sum_f W[l][k][j*64+f]*al[l][j][f]; j>=4 -> ar (head j-4)
// bsum[l][f] = sum_h bias[l][h][f]
__global__ __launch_bounds__(256) void k_prep(const float* __restrict__ W,
                                              const float* __restrict__ al,
                                              const float* __restrict__ ar,
                                              const float* __restrict__ bias,
                                              float* __restrict__ WAB,
                                              float* __restrict__ bsum) {
    int i = blockIdx.x * blockDim.x + threadIdx.x;
    if (i < 4 * 64 * 8) {
        int l = i >> 9, r = i & 511;
        int k = r >> 3, j = r & 7;
        int hh = j & 3;
        const float* wrow = W + (l << 14) + (k << 8) + hh * 64;
        const float* av = ((j < 4) ? al : ar) + (l << 8) + hh * 64;
        float s = 0.f;
        #pragma unroll 8
        for (int f = 0; f < 64; ++f) s = fmaf(wrow[f], av[f], s);
        WAB[i] = s;
    }
    int i2 = i - 4 * 64 * 8;
    if (i2 >= 0 && i2 < 4 * 64) {
        int l = i2 >> 6, f = i2 & 63;
        float s = 0.f;
        #pragma unroll
        for (int h = 0; h < 4; ++h) s += bias[(l << 8) + h * 64 + f];
        bsum[i2] = s;
    }
}

// ================= per-layer kernels =================

// ft = h @ W. Block = 512 thr = 8 waves, 64-row chunk. No W staging:
// W rows read from global (L1/L2-hot, shared by 8 waves). hT[k][row]
// stride 68 (16B-aligned, conflict-free). Wave w: rows w*8..w*8+7,
// lane: cols lane*4..+3. el/er fused via precomputed WAB.
__global__ __launch_bounds__(512, 6) void k_gemm(
        const float* __restrict__ h, const float* __restrict__ Wt,
        const float* __restrict__ WAB,
        __half* __restrict__ ft, float* __restrict__ el, float* __restrict__ er,
        int n) {
    __shared__ float hT[64 * 68];     // 17.4KB, [k][row]
    __shared__ float wab[512];        // 2KB
    int t = threadIdx.x, w = t >> 6, lane = t & 63;
    int r0 = blockIdx.x * 64;

    if (t < 128) ((float4*)wab)[t] = ((const float4*)WAB)[t];

    // stage hT: thread -> row r=t&63, k-range kq*8..+7. Write banks (4k+r)%32:
    // lanes vary r -> 2 lanes/bank (free).
    {
        int r = t & 63, kq = t >> 6;
        int gr = r0 + r;
        float4 a = make_float4(0.f, 0.f, 0.f, 0.f);
        float4 b = make_float4(0.f, 0.f, 0.f, 0.f);
        if (gr < n) {
            const float4* hp = (const float4*)(h + (size_t)gr * 64 + kq * 8);
            a = hp[0]; b = hp[1];
        }
        int k0 = kq * 8;
        hT[(k0 + 0) * 68 + r] = a.x; hT[(k0 + 1) * 68 + r] = a.y;
        hT[(k0 + 2) * 68 + r] = a.z; hT[(k0 + 3) * 68 + r] = a.w;
        hT[(k0 + 4) * 68 + r] = b.x; hT[(k0 + 5) * 68 + r] = b.y;
        hT[(k0 + 6) * 68 + r] = b.z; hT[(k0 + 7) * 68 + r] = b.w;
    }
    __syncthreads();

    float4 acc[8];
    #pragma unroll
    for (int j = 0; j < 8; ++j) acc[j] = make_float4(0.f, 0.f, 0.f, 0.f);
    int c0 = lane << 2;
    int hbase = w * 8;
    const float* Wp = Wt + c0;

    #pragma unroll 4
    for (int k = 0; k < 64; ++k) {
        float4 w4 = *(const float4*)(Wp + (k << 8));            // global, L1-hot
        float4 ha = *(const float4*)&hT[k * 68 + hbase];        // uniform b128
        float4 hb = *(const float4*)&hT[k * 68 + hbase + 4];
        #define FMA4(A, s) { A.x = fmaf(s, w4.x, A.x); A.y = fmaf(s, w4.y, A.y); \
                             A.z = fmaf(s, w4.z, A.z); A.w = fmaf(s, w4.w, A.w); }
        FMA4(acc[0], ha.x) FMA4(acc[1], ha.y) FMA4(acc[2], ha.z) FMA4(acc[3], ha.w)
        FMA4(acc[4], hb.x) FMA4(acc[5], hb.y) FMA4(acc[6], hb.z) FMA4(acc[7], hb.w)
        #undef FMA4
    }

    // store ft as fp16
    #pragma unroll
    for (int j = 0; j < 8; ++j) {
        int gr = r0 + hbase + j;
        if (gr < n) {
            __half2 lo = __floats2half2_rn(acc[j].x, acc[j].y);
            __half2 hi = __floats2half2_rn(acc[j].z, acc[j].w);
            uint2 v = make_uint2(*(unsigned*)&lo, *(unsigned*)&hi);
            *(uint2*)(ft + (size_t)gr * 256 + c0) = v;
        }
    }

    // el/er: thread -> (row r2 = t&63, j = t>>6); hT read conflict-free
    int r2 = t & 63, j = t >> 6;
    float s = 0.f;
    #pragma unroll 8
    for (int k = 0; k < 64; ++k) s = fmaf(hT[k * 68 + r2], wab[(k << 3) + j], s);
    int gr2 = r0 + r2;
    if (gr2 < n) {
        float* dstp = (j < 4) ? el : er;
        dstp[(size_t)gr2 * 4 + (j & 3)] = s;
    }
}

// Fused edge-softmax + aggregation + bias. One wave per dst node.
// First 16-edge chunk kept in registers across both passes (deg<=16 is ~97%).
__global__ __launch_bounds__(256) void k_agg(
        const int* __restrict__ rowptr, const int* __restrict__ csr_src,
        const float* __restrict__ el, const float* __restrict__ er,
        const __half* __restrict__ ft, const float* __restrict__ bsum,
        float* __restrict__ out, int n) {
    __shared__ float lds_ee[4][64];
    __shared__ int   lds_s[4][16];
    int wid  = (int)((blockIdx.x * blockDim.x + threadIdx.x) >> 6);
    int w    = (threadIdx.x >> 6) & 3;
    int lane = threadIdx.x & 63;
    if (wid >= n) return;
    int d = wid;
    int rbeg = rowptr[d], rend = rowptr[d + 1];
    float bs = bsum[lane];
    if (rend == rbeg) { out[(size_t)d * 64 + lane] = bs; return; }

    int ei = lane >> 2, hh = lane & 3;
    float erh = er[(size_t)d * 4 + hh];

    // pass 1: per-head max; chunk 0 cached in registers
    int s0 = -1; float x0 = 0.f;
    float m = -FINF;
    {
        int idx = rbeg + ei;
        if (idx < rend) {
            s0 = csr_src[idx];
            float x = el[(size_t)s0 * 4 + hh] + erh;
            x0 = x > 0.f ? x : NEG_SLOPE * x;
            m = x0;
        }
    }
    for (int base = rbeg + 16; base < rend; base += 16) {
        int idx = base + ei;
        if (idx < rend) {
            int s = csr_src[idx];
            float x = el[(size_t)s * 4 + hh] + erh;
            x = x > 0.f ? x : NEG_SLOPE * x;
            m = fmaxf(m, x);
        }
    }
    #pragma unroll
    for (int msk = 4; msk < 64; msk <<= 1) m = fmaxf(m, __shfl_xor(m, msk));

    // pass 2: chunk 0 from registers, rest re-gathered
    float dsum = 0.f;
    float4 acc = make_float4(0.f, 0.f, 0.f, 0.f);
    {
        float ee = 0.f;
        if (s0 >= 0) {
            ee = __expf(x0 - m);
            dsum += ee;
            if (hh == 0) lds_s[w][ei] = s0;
        }
        lds_ee[w][lane] = ee;
        int e16 = min(16, rend - rbeg);
        for (int i = 0; i < e16; ++i) {
            float4 ee4 = *(float4*)&lds_ee[w][i * 4];
            int s = lds_s[w][i];
            uint2 u = *(const uint2*)(ft + (size_t)s * 256 + (lane << 2));
            float2 fa = __half22float2(*(__half2*)&u.x);
            float2 fb = __half22float2(*(__half2*)&u.y);
            acc.x += ee4.x * fa.x; acc.y += ee4.y * fa.y;
            acc.z += ee4.z * fb.x; acc.w += ee4.w * fb.y;
        }
    }
    for (int base = rbeg + 16; base < rend; base += 16) {
        int idx = base + ei;
        int e16 = min(16, rend - base);
        float ee = 0.f;
        if (idx < rend) {
            int s = csr_src[idx];
            float x = el[(size_t)s * 4 + hh] + erh;
            x = x > 0.f ? x : NEG_SLOPE * x;
            ee = __expf(x - m);
            dsum += ee;
            if (hh == 0) lds_s[w][ei] = s;
        }
        lds_ee[w][lane] = ee;
        for (int i = 0; i < e16; ++i) {
            float4 ee4 = *(float4*)&lds_ee[w][i * 4];
            int s = lds_s[w][i];
            uint2 u = *(const uint2*)(ft + (size_t)s * 256 + (lane << 2));
            float2 fa = __half22float2(*(__half2*)&u.x);
            float2 fb = __half22float2(*(__half2*)&u.y);
            acc.x += ee4.x * fa.x; acc.y += ee4.y * fa.y;
            acc.z += ee4.z * fb.x; acc.w += ee4.w * fb.y;
        }
    }
    #pragma unroll
    for (int msk = 4; msk < 64; msk <<= 1) dsum += __shfl_xor(dsum, msk);
    float d0 = __shfl(dsum, 0), d1 = __shfl(dsum, 1);
    float d2 = __shfl(dsum, 2), d3 = __shfl(dsum, 3);
    out[(size_t)d * 64 + lane] = acc.x / d0 + acc.y / d1 + acc.z / d2 + acc.w / d3 + bs;
}

// ================= launcher =================

extern "C" void kernel_launch(void* const* d_in, const int* in_sizes, int n_in,
                              void* d_out, int out_size, void* d_ws, size_t ws_size,
                              hipStream_t stream) {
    const float* feat = (const float*)d_in[0];
    const float* W    = (const float*)d_in[1];
    const float* al   = (const float*)d_in[2];
    const float* ar   = (const float*)d_in[3];
    const float* bias = (const float*)d_in[4];
    const int*   src  = (const int*)d_in[5];
    const int*   dst  = (const int*)d_in[6];
    float* out = (float*)d_out;

    const int N = in_sizes[0] / 64;   // 50000
    const int E = in_sizes[5];        // 500000
    const int L = 4;

    // workspace carve
    float* ws = (float*)d_ws;
    __half* ft = (__half*)ws;                          // N*256 halves = N*128 floats
    float* hA   = ws + (size_t)N * 128;                // N*64
    float* hB   = hA + (size_t)N * 64;                 // N*64
    float* el   = hB + (size_t)N * 64;                 // N*4
    float* er   = el + (size_t)N * 4;                  // N*4
    float* Wt   = er + (size_t)N * 4;                  // 4*16384
    float* WAB  = Wt + 4 * 16384;                      // 4*512
    float* bsum = WAB + 4 * 512;                       // 4*64
    int* rowptr  = (int*)(bsum + 4 * 64);              // N+1
    int* cursor  = rowptr + (N + 1);                   // N
    int* deg     = cursor + N;                         // N
    int* csr_src = deg + N;                            // E

    // ---- prologue: CSR build + weight prep (once per call) ----
    hipMemsetAsync(deg, 0, (size_t)N * sizeof(int), stream);
    k_deg<<<(E + 255) / 256, 256, 0, stream>>>(dst, deg, E);
    k_scan<<<1, 1024, 0, stream>>>(deg, rowptr, cursor, N);
    k_scatter<<<(E + 255) / 256, 256, 0, stream>>>(src, dst, cursor, csr_src, E);
    k_transW<<<(4 * 64 * 256 + 255) / 256, 256, 0, stream>>>(W, Wt);
    k_prep<<<(4 * 64 * 8 + 4 * 64 + 255) / 256, 256, 0, stream>>>(
        W, al, ar, bias, WAB, bsum);

    // ---- layers ----
    const float* hin = feat;
    for (int l = 0; l < L; ++l) {
        float* hout = (l == L - 1) ? out : ((l & 1) ? hB : hA);
        k_gemm<<<(N + 63) / 64, 512, 0, stream>>>(
            hin, Wt + (size_t)l * 16384, WAB + (size_t)l * 512,
            ft, el, er, N);
        k_agg<<<((size_t)N * 64 + 255) / 256, 256, 0, stream>>>(
            rowptr, csr_src, el, er, ft, bsum + (size_t)l * 64, hout, N);
        hin = hout;
    }
}